// Round 7
// baseline (513.541 us; speedup 1.0000x reference)
//
#include <hip/hip_runtime.h>
#include <math.h>

#define NPTS 50000
#define NG   128
#define DD   32
#define FF   64
#define AA   8
#define HINC 1120   // DD + FF + 2*FF*AA
#define EPSV 1e-5f
#define CH   64
#define NCHUNK ((NPTS + CH - 1) / CH)   // 782
#define NCELL (NG * 512)                // per-layer agg cells

#define SC_AGG  4294967296.0f           // 2^32
#define ISC_AGG 2.3283064365386963e-10
#define SC_ST   1073741824.0f           // 2^30
#define ISC_ST  9.313225746154785e-10

__device__ __forceinline__ float tanh_fast(float x) {
    float e = __expf(-2.f * fabsf(x));
    float r = __fdividef(1.f - e, 1.f + e);
    return copysignf(r, x);
}
// monotonic float <-> uint map (for atomicMax over signed floats)
__device__ __forceinline__ unsigned fmap(float f) {
    unsigned b = __float_as_uint(f);
    return (b & 0x80000000u) ? ~b : (b | 0x80000000u);
}
__device__ __forceinline__ float funmap(unsigned u) {
    return (u & 0x80000000u) ? __uint_as_float(u & 0x7FFFFFFFu) : __uint_as_float(~u);
}
__device__ __forceinline__ void ln_scale(const unsigned long long* sLL, float& gm, float& ginv) {
    const double invM = 1.0 / ((double)NPTS * DD);
    double s1 = (double)(long long)sLL[0] * ISC_ST;
    double s2 = (double)(long long)sLL[1] * ISC_ST;
    double md = s1 * invM;
    double vd = s2 * invM - md * md;
    gm = (float)md;
    ginv = 1.f / (sqrtf(fmaxf((float)vd, 0.f)) + EPSV);
}

// ---------------------------------------------------------------- setup: offs + Weff/beff fold (stats/agg zeroed by memset)
__global__ __launch_bounds__(256) void k_setup(const int* __restrict__ batch,
                                               const float* __restrict__ W_in,
                                               const float* __restrict__ b_in,
                                               const float* __restrict__ W_out,
                                               const float* __restrict__ b_out,
                                               int* __restrict__ offs,
                                               float* __restrict__ Weff,
                                               float* __restrict__ beff) {
    int t = threadIdx.x, bid = blockIdx.x;
    if (bid == 0) {
        if (t <= NG) {
            int lo = 0, hi = NPTS;
            while (lo < hi) { int mid = (lo+hi)>>1; if (batch[mid] < t) lo = mid+1; else hi = mid; }
            offs[t] = lo;
        }
    } else {
        int j = bid - 1;
        const float* W0 = W_out + (size_t)j*HINC*DD;   // rows 0..31
        const float* W1 = W0 + DD*DD;                  // rows 32..95
        const float* Wi = W_in + (size_t)j*DD*FF;
        for (int e = t; e < DD*DD; e += 256) {
            int i = e >> 5, d = e & 31;
            float s = W0[e];
            for (int f = 0; f < FF; f++) s += Wi[i*FF+f] * W1[f*DD+d];
            Weff[j*DD*DD + e] = s;
        }
        if (t < DD) {
            float s = b_out[j*DD + t];
            for (int f = 0; f < FF; f++) s += b_in[j*FF+f] * W1[f*DD+t];
            beff[j*DD + t] = s;
        }
    }
}

// ---------------------------------------------------------------- kA: (embed|gln) -> xp -> attn -> atomic agg (sum fixed-point, max uint-map)
__global__ __launch_bounds__(512) void k_A(const float* __restrict__ x,
                                           const float* __restrict__ Wi,
                                           const float* __restrict__ bi,
                                           const float* __restrict__ lniw,
                                           const float* __restrict__ lnib,
                                           const float* __restrict__ inb,
                                           const unsigned long long* __restrict__ statsLL,
                                           const float* __restrict__ gw,
                                           const float* __restrict__ gb,
                                           const float* __restrict__ Win,
                                           const float* __restrict__ bin,
                                           const float* __restrict__ Wsc,
                                           const float* __restrict__ bsc,
                                           const int* __restrict__ batch,
                                           unsigned long long* __restrict__ aggS,
                                           unsigned int* __restrict__ aggM,
                                           float* __restrict__ hout,
                                           int isL0) {
    __shared__ float sxp[CH][68];      // padded: conflict-free
    __shared__ float sattn[CH][9];
    __shared__ float sWin[DD*FF];
    __shared__ float sScT[AA*FF];      // Wsc transposed [a][f]
    __shared__ int   sbat[CH];

    const int t = threadIdx.x;
    const int b0 = blockIdx.x * CH;
    const int np = min(CH, NPTS - b0);

    for (int k = t; k < DD*FF; k += 512) sWin[k] = Win[k];
    { int a = t >> 6, f = t & 63; sScT[t] = Wsc[f*AA + a]; }   // 512 == AA*FF
    if (t < CH) sbat[t] = batch[min(b0 + t, NPTS-1)];

    float gm = 0.f, ginv = 1.f;
    if (!isL0) ln_scale(statsLL, gm, ginv);

    const int pt = t >> 3, q = t & 7;
    const int fo = q * 8;
    const int n = b0 + pt;
    float hr4[4] = {0.f, 0.f, 0.f, 0.f};
    // ---- phase 1 (registers): embed for L0, gln-load otherwise
    if (pt < np) {
        const int d4 = q * 4;
        if (isL0) {
            float x0 = x[n*3], x1 = x[n*3+1], x2 = x[n*3+2];
            float tv0 = x0*Wi[d4+0] + x1*Wi[DD+d4+0] + x2*Wi[2*DD+d4+0] + bi[d4+0];
            float tv1 = x0*Wi[d4+1] + x1*Wi[DD+d4+1] + x2*Wi[2*DD+d4+1] + bi[d4+1];
            float tv2 = x0*Wi[d4+2] + x1*Wi[DD+d4+2] + x2*Wi[2*DD+d4+2] + bi[d4+2];
            float tv3 = x0*Wi[d4+3] + x1*Wi[DD+d4+3] + x2*Wi[2*DD+d4+3] + bi[d4+3];
            float sm = (tv0+tv1) + (tv2+tv3);
            sm += __shfl_xor(sm, 1); sm += __shfl_xor(sm, 2); sm += __shfl_xor(sm, 4);
            float mm = sm * (1.f/DD);
            float c0 = tv0-mm, c1 = tv1-mm, c2 = tv2-mm, c3 = tv3-mm;
            float qq = (c0*c0 + c1*c1) + (c2*c2 + c3*c3);
            qq += __shfl_xor(qq, 1); qq += __shfl_xor(qq, 2); qq += __shfl_xor(qq, 4);
            float inv = 1.f/sqrtf(qq*(1.f/DD) + EPSV);
            hr4[0] = tanh_fast(c0*inv*lniw[d4+0] + lnib[d4+0]);
            hr4[1] = tanh_fast(c1*inv*lniw[d4+1] + lnib[d4+1]);
            hr4[2] = tanh_fast(c2*inv*lniw[d4+2] + lnib[d4+2]);
            hr4[3] = tanh_fast(c3*inv*lniw[d4+3] + lnib[d4+3]);
            *(float4*)&hout[(size_t)n*DD + d4] = make_float4(hr4[0],hr4[1],hr4[2],hr4[3]);
        } else {
            float4 v = *(const float4*)&inb[(size_t)n*DD + d4];
            float4 w4 = *(const float4*)&gw[d4];
            float4 b4 = *(const float4*)&gb[d4];
            hr4[0] = (v.x-gm)*ginv*w4.x + b4.x;
            hr4[1] = (v.y-gm)*ginv*w4.y + b4.y;
            hr4[2] = (v.z-gm)*ginv*w4.z + b4.z;
            hr4[3] = (v.w-gm)*ginv*w4.w + b4.w;
        }
    }
    __syncthreads();   // sWin/sScT/sbat staged
    // ---- phase 2: xp + attn (8 threads per point, h via wave shuffle)
    if (pt < np) {
        float4 bi0 = *(const float4*)&bin[fo];
        float4 bi1 = *(const float4*)&bin[fo+4];
        float xr[8] = {bi0.x,bi0.y,bi0.z,bi0.w,bi1.x,bi1.y,bi1.z,bi1.w};
        #pragma unroll
        for (int k = 0; k < DD; k++) {
            float hv = __shfl(hr4[k & 3], (t & 56) | (k >> 2), 64);
            float4 wa = *(const float4*)&sWin[k*FF + fo];
            float4 wb = *(const float4*)&sWin[k*FF + fo + 4];
            xr[0] += hv*wa.x; xr[1] += hv*wa.y; xr[2] += hv*wa.z; xr[3] += hv*wa.w;
            xr[4] += hv*wb.x; xr[5] += hv*wb.y; xr[6] += hv*wb.z; xr[7] += hv*wb.w;
        }
        float pa[8];
        #pragma unroll
        for (int a = 0; a < 8; a++) {
            float4 wa = *(const float4*)&sScT[a*FF + fo];
            float4 wb = *(const float4*)&sScT[a*FF + fo + 4];
            pa[a] = xr[0]*wa.x + xr[1]*wa.y + xr[2]*wa.z + xr[3]*wa.w
                  + xr[4]*wb.x + xr[5]*wb.y + xr[6]*wb.z + xr[7]*wb.w;
        }
        #pragma unroll
        for (int msk = 1; msk < 8; msk <<= 1) {
            #pragma unroll
            for (int a = 0; a < 8; a++) pa[a] += __shfl_xor(pa[a], msk);
        }
        sattn[pt][q] = __expf(-fabsf(pa[q] + bsc[q]));
        *(float4*)&sxp[pt][fo]   = make_float4(xr[0],xr[1],xr[2],xr[3]);
        *(float4*)&sxp[pt][fo+4] = make_float4(xr[4],xr[5],xr[6],xr[7]);
    }
    __syncthreads();
    // ---- phase 3: one (a,f) cell per thread, segmented over sorted batch
    const int ca = t >> 6, cf = t & 63;
    float csum = 0.f, cmax = -INFINITY;
    int curg = sbat[0];
    for (int pp = 0; pp < np; pp++) {
        int g = sbat[pp];                 // block-uniform branch
        if (g != curg) {
            atomicAdd(&aggS[(size_t)curg*512 + t],
                      (unsigned long long)(long long)llrintf(csum * SC_AGG));
            atomicMax(&aggM[(size_t)curg*512 + t], fmap(cmax));
            csum = 0.f; cmax = -INFINITY; curg = g;
        }
        float w = sattn[pp][ca] * sxp[pp][cf];
        csum += w;
        cmax = fmaxf(cmax, w);
    }
    atomicAdd(&aggS[(size_t)curg*512 + t],
              (unsigned long long)(long long)llrintf(csum * SC_AGG));
    atomicMax(&aggM[(size_t)curg*512 + t], fmap(cmax));
}

// ---------------------------------------------------------------- kC: agg readback -> aggW (per graph window) -> out = tanh(gln@Weff + aggW) + stats
__global__ __launch_bounds__(512) void k_C(const float* __restrict__ inb,
                                           const unsigned long long* __restrict__ statsLL,
                                           const float* __restrict__ gw,
                                           const float* __restrict__ gb,
                                           const int* __restrict__ batch,
                                           const int* __restrict__ offs,
                                           const unsigned long long* __restrict__ aggS,
                                           const unsigned int* __restrict__ aggM,
                                           const float* __restrict__ Wagg,   // W_out[j] + 96*DD
                                           const float* __restrict__ beff,
                                           const float* __restrict__ Weff,
                                           float* __restrict__ tbuf,
                                           unsigned long long* __restrict__ statsO,
                                           int isL0) {
    __shared__ float sW[DD][36];
    __shared__ float agg[2*FF*AA];     // 1024
    __shared__ float red[16][DD];
    __shared__ float aggWs[8][DD];
    __shared__ float rs1[8], rs2[8];
    const int t = threadIdx.x;
    for (int k = t; k < DD*DD; k += 512) sW[k>>5][k&31] = Weff[k];

    float gm = 0.f, ginv = 1.f;
    if (!isL0) ln_scale(statsLL, gm, ginv);

    const int b0 = blockIdx.x * CH;
    const int np = min(CH, NPTS - b0);
    const int pt = t >> 3, q = t & 7, d4 = q * 4;
    const int n = b0 + pt;
    float hr4[4] = {0.f, 0.f, 0.f, 0.f};
    if (pt < np) {
        float4 v = *(const float4*)&inb[(size_t)n*DD + d4];
        if (isL0) {
            hr4[0] = v.x; hr4[1] = v.y; hr4[2] = v.z; hr4[3] = v.w;
        } else {
            float4 w4 = *(const float4*)&gw[d4];
            float4 b4 = *(const float4*)&gb[d4];
            hr4[0] = (v.x-gm)*ginv*w4.x + b4.x;
            hr4[1] = (v.y-gm)*ginv*w4.y + b4.y;
            hr4[2] = (v.z-gm)*ginv*w4.z + b4.z;
            hr4[3] = (v.w-gm)*ginv*w4.w + b4.w;
        }
    }
    const int myg = (pt < np) ? batch[n] : -1;
    const int g0 = batch[b0];
    const int g1 = batch[min(b0 + np - 1, NPTS-1)];
    float s1 = 0.f, s2 = 0.f;
    for (int gbase = g0; gbase <= g1; gbase += 8) {
        int ng = min(8, g1 - gbase + 1);
        for (int gi = 0; gi < ng; gi++) {
            int g = gbase + gi;
            int cnt = offs[g+1] - offs[g];
            long long S = (long long)aggS[(size_t)g*512 + t];
            unsigned M = aggM[(size_t)g*512 + t];
            float mean, mx;
            if (cnt > 0) {
                mean = (float)((double)S * ISC_AGG / (double)cnt);
                mx = funmap(M);
            } else { mean = 0.f; mx = 0.f; }
            int a = t >> 6, f = t & 63;
            agg[a*2*FF + f]      = mean;
            agg[a*2*FF + FF + f] = mx;
            __syncthreads();
            int d = t & 31, grp = t >> 5;
            float acc = 0.f;
            #pragma unroll
            for (int k2 = 0; k2 < 64; k2++) {
                int k = grp*64 + k2;
                acc += agg[k] * Wagg[k*DD + d];
            }
            red[grp][d] = acc;
            __syncthreads();
            if (t < DD) {
                float r = 0.f;
                #pragma unroll
                for (int q16 = 0; q16 < 16; q16++) r += red[q16][t];
                aggWs[gi][t] = r + beff[t];
            }
            __syncthreads();   // aggWs[gi] ready; agg reusable next gi
        }
        if (pt < np && myg >= gbase && myg < gbase + ng) {
            int gi = myg - gbase;
            float4 a0 = *(const float4*)&aggWs[gi][d4];
            float acc0 = a0.x, acc1 = a0.y, acc2 = a0.z, acc3 = a0.w;
            #pragma unroll
            for (int k = 0; k < DD; k++) {
                float hv = __shfl(hr4[k & 3], (t & 56) | (k >> 2), 64);
                float4 w = *(const float4*)&sW[k][d4];
                acc0 += hv*w.x; acc1 += hv*w.y; acc2 += hv*w.z; acc3 += hv*w.w;
            }
            float4 o;
            o.x = tanh_fast(acc0); o.y = tanh_fast(acc1);
            o.z = tanh_fast(acc2); o.w = tanh_fast(acc3);
            *(float4*)&tbuf[(size_t)n*DD + d4] = o;
            s1 += (o.x + o.y) + (o.z + o.w);
            s2 += (o.x*o.x + o.y*o.y) + (o.z*o.z + o.w*o.w);
        }
        __syncthreads();       // protect aggWs before next window
    }
    // block reduce -> fixed-point atomics (deterministic)
    #pragma unroll
    for (int o = 32; o > 0; o >>= 1) { s1 += __shfl_down(s1, o); s2 += __shfl_down(s2, o); }
    int wid = t >> 6;
    if ((t & 63) == 0) { rs1[wid] = s1; rs2[wid] = s2; }
    __syncthreads();
    if (t == 0) {
        float a1 = 0.f, a2 = 0.f;
        #pragma unroll
        for (int qq = 0; qq < 8; qq++) { a1 += rs1[qq]; a2 += rs2[qq]; }
        atomicAdd(&statsO[0], (unsigned long long)(long long)llrintf(a1 * SC_ST));
        atomicAdd(&statsO[1], (unsigned long long)(long long)llrintf(a2 * SC_ST));
    }
}

// ---------------------------------------------------------------- readout: segment mean of gln(tbuf) -> 3x (dense+ln+tanh) -> dot
__global__ __launch_bounds__(256) void k_read(const float* __restrict__ tbuf,
                                              const unsigned long long* __restrict__ statsLL,
                                              const float* __restrict__ gw,
                                              const float* __restrict__ gb,
                                              const int* __restrict__ offs,
                                              const float* __restrict__ Wp,
                                              const float* __restrict__ bp,
                                              const float* __restrict__ lnw,
                                              const float* __restrict__ lnb,
                                              const float* __restrict__ Wpo,
                                              const float* __restrict__ bpo,
                                              float* __restrict__ out) {
    int g = blockIdx.x;
    int t = threadIdx.x;
    int d = t & 31, pl = t >> 5;   // 8 point-lanes x 32 dims
    int s0 = offs[g], e0 = offs[g+1];
    float acc = 0.f;
    for (int n = s0 + pl; n < e0; n += 8) acc += tbuf[(size_t)n*DD + d];
    __shared__ float red[8][DD];
    red[pl][d] = acc;
    __syncthreads();
    __shared__ float sv[DD];
    if (t < DD) {
        float r = 0.f;
        #pragma unroll
        for (int qq = 0; qq < 8; qq++) r += red[qq][t];
        float gm, ginv;
        ln_scale(statsLL, gm, ginv);
        float cnt = (float)(e0 - s0);
        float mean = r / fmaxf(cnt, 1.f);
        sv[t] = (e0 > s0) ? (mean - gm)*ginv*gw[t] + gb[t] : 0.f;
    }
    __syncthreads();
    for (int j = 0; j < 3; j++) {
        float yv = 0.f;
        if (t < DD) {
            float y = bp[j*DD + t];
            #pragma unroll
            for (int i = 0; i < DD; i++) y += sv[i] * Wp[j*DD*DD + i*DD + t];
            float sum = y;
            #pragma unroll
            for (int o = 1; o < 32; o <<= 1) sum += __shfl_xor(sum, o);
            float m = sum * (1.f/DD);
            float c = y - m;
            float sq = c*c;
            #pragma unroll
            for (int o = 1; o < 32; o <<= 1) sq += __shfl_xor(sq, o);
            float var = sq * (1.f/DD);
            yv = tanh_fast(c / sqrtf(var + EPSV) * lnw[j*DD+t] + lnb[j*DD+t]);
        }
        __syncthreads();
        if (t < DD) sv[t] = yv;
        __syncthreads();
    }
    if (t < DD) {
        float p = sv[t] * Wpo[t];
        #pragma unroll
        for (int o = 1; o < 32; o <<= 1) p += __shfl_xor(p, o);
        if (t == 0) out[g] = p + bpo[0];
    }
}

extern "C" void kernel_launch(void* const* d_in, const int* in_sizes, int n_in,
                              void* d_out, int out_size, void* d_ws, size_t ws_size,
                              hipStream_t stream) {
    const float* x     = (const float*)d_in[0];
    const int*   batch = (const int*)  d_in[1];
    const float* Wi    = (const float*)d_in[2];
    const float* bi    = (const float*)d_in[3];
    const float* lni_w = (const float*)d_in[4];
    const float* lni_b = (const float*)d_in[5];
    const float* W_in  = (const float*)d_in[6];
    const float* b_in  = (const float*)d_in[7];
    const float* W_sc  = (const float*)d_in[8];
    const float* b_sc  = (const float*)d_in[9];
    const float* W_out = (const float*)d_in[10];
    const float* b_out = (const float*)d_in[11];
    const float* gln_w = (const float*)d_in[12];
    const float* gln_b = (const float*)d_in[13];
    const float* Wp    = (const float*)d_in[14];
    const float* bp    = (const float*)d_in[15];
    const float* lnp_w = (const float*)d_in[16];
    const float* lnp_b = (const float*)d_in[17];
    const float* Wpo   = (const float*)d_in[18];
    const float* bpo   = (const float*)d_in[19];
    float* out = (float*)d_out;

    // workspace layout: zeroed region first (aggS | statsLL | aggM), then floats
    unsigned long long* aggS    = (unsigned long long*)d_ws;       // 9 * NCELL
    unsigned long long* statsLL = aggS + (size_t)9*NCELL;          // 32 (2 per layer)
    unsigned int*       aggM    = (unsigned int*)(statsLL + 32);   // 9 * NCELL
    float* h    = (float*)(aggM + (size_t)9*NCELL);                // NPTS*32
    float* tbuf = h + (size_t)NPTS*DD;                             // NPTS*32
    float* Weff = tbuf + (size_t)NPTS*DD;                          // 3*1024
    float* beff = Weff + 3*DD*DD;                                  // 96
    int*   offs = (int*)(beff + 3*DD);                             // NG+1
    size_t zbytes = (char*)(aggM + (size_t)9*NCELL) - (char*)d_ws;

    hipMemsetAsync(d_ws, 0, zbytes, stream);
    k_setup<<<4, 256, 0, stream>>>(batch, W_in, b_in, W_out, b_out, offs, Weff, beff);

    for (int L = 0; L < 9; ++L) {
        int j = L % 3;
        int pj = (L + 2) % 3;
        const float* inb = L ? tbuf : h;
        const unsigned long long* st = L ? statsLL + 2*(L-1) : statsLL;
        const float* pgw = gln_w + pj*DD;
        const float* pgb = gln_b + pj*DD;
        k_A<<<NCHUNK, 512, 0, stream>>>(
            x, Wi, bi, lni_w, lni_b,
            inb, st, pgw, pgb,
            W_in + (size_t)j*DD*FF, b_in + j*FF,
            W_sc + (size_t)j*FF*AA, b_sc + j*AA,
            batch, aggS + (size_t)L*NCELL, aggM + (size_t)L*NCELL,
            h, (L == 0) ? 1 : 0);
        k_C<<<NCHUNK, 512, 0, stream>>>(
            inb, st, pgw, pgb, batch, offs,
            aggS + (size_t)L*NCELL, aggM + (size_t)L*NCELL,
            W_out + (size_t)j*HINC*DD + (size_t)96*DD, beff + j*DD,
            Weff + (size_t)j*DD*DD, tbuf, statsLL + 2*L, (L == 0) ? 1 : 0);
    }
    k_read<<<NG, 256, 0, stream>>>(tbuf, statsLL + 16, gln_w + 2*DD, gln_b + 2*DD,
                                   offs, Wp, bp, lnp_w, lnp_b, Wpo, bpo, out);
}